// Round 10
// baseline (168.615 us; speedup 1.0000x reference)
//
#include <hip/hip_runtime.h>
#include <hip/hip_bf16.h>
#include <math.h>

// Sizes fixed by the reference.
#define T_PTS 400
#define D_OUT 10000
#define L12   1200
#define L3    800
#define N_TASKS 30000          // 3 matrices x 10000 rows
#define N_WAVES 4096           // 1024 blocks x 4 waves

// Workspace layout (floats):
//   [0, 3328)           feature vector (3203 used, padded)
//   [3328, 3328+30000)  partial[m*10000 + row] = dot(Wm[row], feat_m)
#define PART_OFF 3328
#define WS_NEED ((3328 + N_TASKS) * sizeof(float))

// ---------------------------------------------------------------------------
// Kernel 1: build the feature vector from input (T,4) into ws.
// ---------------------------------------------------------------------------
__global__ __launch_bounds__(512)
void hdc_features_kernel(const float* __restrict__ in, float* __restrict__ feat) {
    __shared__ float red[3][8];
    const int tid = threadIdx.x;          // 0..511
    float ex = 0.f, ey = 0.f, ez = 0.f;

    if (tid < T_PTS) {
        const float4 cur = reinterpret_cast<const float4*>(in)[tid];
        const float x = cur.y, y = cur.z, z = cur.w;
        feat[tid]        = x;
        feat[400 + tid]  = y;
        feat[800 + tid]  = z;
        feat[2400 + tid] = sqrtf(x * x + y * y + z * z);
        ex = x * x; ey = y * y; ez = z * z;

        float jx = 0.f, jy = 0.f, jz = 0.f;
        if (tid > 0) {
            const float4 prev = reinterpret_cast<const float4*>(in)[tid - 1];
            const float dt = cur.x - prev.x;           // t0 offset cancels
            const float inv = 1.0f / dt;
            jx = (x - prev.y) * inv;
            jy = (y - prev.z) * inv;
            jz = (z - prev.w) * inv;
        }
        feat[1200 + tid] = jx;
        feat[1600 + tid] = jy;
        feat[2000 + tid] = jz;
        feat[2800 + tid] = sqrtf(jx * jx + jy * jy + jz * jz);
    }

    #pragma unroll
    for (int off = 32; off; off >>= 1) {
        ex += __shfl_down(ex, off, 64);
        ey += __shfl_down(ey, off, 64);
        ez += __shfl_down(ez, off, 64);
    }
    const int wave = tid >> 6, lane = tid & 63;
    if (lane == 0) { red[0][wave] = ex; red[1][wave] = ey; red[2][wave] = ez; }
    __syncthreads();
    if (tid == 0) {
        float sx = 0.f, sy = 0.f, sz = 0.f;
        #pragma unroll
        for (int w = 0; w < 8; ++w) { sx += red[0][w]; sy += red[1][w]; sz += red[2][w]; }
        const float invT = 1.0f / (float)T_PTS;
        feat[3200] = sx * invT;
        feat[3201] = sy * invT;
        feat[3202] = sz * invT;
    }
}

// ---------------------------------------------------------------------------
// Kernel 2: pipelined row-dot. One wave = one (matrix,row) task per loop
// iteration: 5 weight loads (1KB each, coalesced) + 5 L1-hit feature loads
// issued together -> 5-10KB in flight per wave; per-thread FMA accumulate;
// ONE shuffle reduce per 5KB (amortized 5x vs R9's per-1KB reduce); one
// partial store. 4096 waves x 7-8 grid-stride tasks.
// Little's law: 16 waves/CU x 5KB x ~0.6 duty ~= 48KB in flight >> 9-15KB
// needed to saturate HBM (R9's failure: 1KB x 0.24 x 21 = 5KB).
// r[5]+s[5] = 40 staging VGPRs under a 128 cap: no spill, no serialization
// (R7's failure: 13 float4s under a 56-VGPR budget -> batched loads).
// ---------------------------------------------------------------------------
__global__ __launch_bounds__(256, 4)
void hdc_dot_pipe(const float* __restrict__ W1, const float* __restrict__ W2,
                  const float* __restrict__ W3, const float* __restrict__ feat,
                  float* __restrict__ partial) {
    const int wv   = blockIdx.x * 4 + (threadIdx.x >> 6);  // 0..4095
    const int lane = threadIdx.x & 63;
    const int c0   = lane * 4;
    const float4 z4 = make_float4(0.f, 0.f, 0.f, 0.f);

    for (int t = wv; t < N_TASKS; t += N_WAVES) {
        const int m   = (t >= 20000) ? 2 : ((t >= 10000) ? 1 : 0);
        const int row = t - m * 10000;
        const float* __restrict__ Wm = (m == 0) ? W1 : ((m == 1) ? W2 : W3);
        const int len = (m == 2) ? L3 : L12;
        const float* __restrict__ wr = Wm + (size_t)row * len;
        const float* __restrict__ fr = feat + m * 1200;

        // Issue all weight loads (HBM/LLC), then feature loads (L1 broadcast).
        float4 r[5], s[5];
        #pragma unroll
        for (int i = 0; i < 5; ++i) {
            const int k = c0 + 256 * i;
            r[i] = (k < len) ? *reinterpret_cast<const float4*>(wr + k) : z4;
        }
        #pragma unroll
        for (int i = 0; i < 5; ++i) {
            const int k = c0 + 256 * i;
            s[i] = (k < len) ? *reinterpret_cast<const float4*>(fr + k) : z4;
        }

        float a = 0.f;
        #pragma unroll
        for (int i = 0; i < 5; ++i)
            a += r[i].x * s[i].x + r[i].y * s[i].y + r[i].z * s[i].z + r[i].w * s[i].w;

        #pragma unroll
        for (int off = 32; off; off >>= 1) a += __shfl_down(a, off, 64);
        if (lane == 0) partial[t] = a;
    }
}

// ---------------------------------------------------------------------------
// Kernel 3: combine 3 partial dots per row + 4-way tanh epilogue.
// ---------------------------------------------------------------------------
__global__ __launch_bounds__(256)
void hdc_tanh_kernel(const float* __restrict__ partial,
                     const float* __restrict__ b1, const float* __restrict__ b2,
                     const float* __restrict__ b3, const float* __restrict__ W4,
                     const float* __restrict__ b4, const float* __restrict__ feat,
                     float* __restrict__ out) {
    const int d = blockIdx.x * 256 + threadIdx.x;
    if (d >= D_OUT) return;
    const float a1 = partial[d];
    const float a2 = partial[10000 + d];
    const float a3 = partial[20000 + d];
    const float e0 = feat[3200], e1 = feat[3201], e2 = feat[3202];
    const float hv1 = tanhf(a1 + b1[d]);
    const float hv2 = tanhf(a2 + b2[d]);
    const float hv3 = tanhf(a3 + b3[d]);
    const float hv4 = tanhf(W4[(size_t)d * 3 + 0] * e0 +
                            W4[(size_t)d * 3 + 1] * e1 +
                            W4[(size_t)d * 3 + 2] * e2 + b4[d]);
    out[d] = tanhf(hv1 * hv4 + hv2 + hv3);
}

// ---------------------------------------------------------------------------
// Fallback (R7 design, proven) if ws is unexpectedly small.
// ---------------------------------------------------------------------------
__global__ __launch_bounds__(256)
void hdc_gemv_fallback(const float* __restrict__ W1, const float* __restrict__ b1,
                       const float* __restrict__ W2, const float* __restrict__ b2,
                       const float* __restrict__ W3, const float* __restrict__ b3,
                       const float* __restrict__ W4, const float* __restrict__ b4,
                       const float* __restrict__ feat, float* __restrict__ out) {
    __shared__ __align__(16) float g[3203];
    const int tid = threadIdx.x;
    const int wave = tid >> 6, lane = tid & 63;
    const int d = blockIdx.x * 4 + wave;
    const int c0 = lane * 4;

    const float* __restrict__ w1 = W1 + (size_t)d * L12;
    const float* __restrict__ w2 = W2 + (size_t)d * L12;
    const float* __restrict__ w3 = W3 + (size_t)d * L3;

    float4 r[12];
    #pragma unroll
    for (int i = 0; i < 12; ++i) {
        const int k = 256 * i + c0;
        const float* p;
        if (i < 4)       p = w1 + k;
        else if (i == 4) p = (k < L12) ? (w1 + k) : (w2 + (k - L12));
        else if (i < 9)  p = w2 + (k - L12);
        else if (i == 9) p = (k < 2400) ? (w2 + (k - L12)) : (w3 + (k - 2400));
        else             p = w3 + (k - 2400);
        r[i] = *reinterpret_cast<const float4*>(p);
    }
    const float2 rt = *reinterpret_cast<const float2*>(w3 + 672 + 2 * lane);

    {
        float4* g4 = reinterpret_cast<float4*>(g);
        const float4* feat4 = reinterpret_cast<const float4*>(feat);
        for (int i = tid; i < 800; i += 256) g4[i] = feat4[i];
        if (tid == 0) { g[3200] = feat[3200]; g[3201] = feat[3201]; g[3202] = feat[3202]; }
    }
    __syncthreads();

    float acc1 = 0.f, acc2 = 0.f, acc3 = 0.f;
    #pragma unroll
    for (int i = 0; i < 12; ++i) {
        const int k = 256 * i + c0;
        const float4 s = *reinterpret_cast<const float4*>(&g[k]);
        const float t = r[i].x * s.x + r[i].y * s.y + r[i].z * s.z + r[i].w * s.w;
        if (i < 4)       acc1 += t;
        else if (i == 4) { acc1 += (k < L12) ? t : 0.f; acc2 += (k < L12) ? 0.f : t; }
        else if (i < 9)  acc2 += t;
        else if (i == 9) { acc2 += (k < 2400) ? t : 0.f; acc3 += (k < 2400) ? 0.f : t; }
        else             acc3 += t;
    }
    {
        const int k = 3072 + 2 * lane;
        acc3 += rt.x * g[k] + rt.y * g[k + 1];
    }

    #pragma unroll
    for (int off = 32; off; off >>= 1) {
        acc1 += __shfl_down(acc1, off, 64);
        acc2 += __shfl_down(acc2, off, 64);
        acc3 += __shfl_down(acc3, off, 64);
    }

    if (lane == 0) {
        const float e0 = g[3200], e1 = g[3201], e2 = g[3202];
        const float hv1 = tanhf(acc1 + b1[d]);
        const float hv2 = tanhf(acc2 + b2[d]);
        const float hv3 = tanhf(acc3 + b3[d]);
        const float hv4 = tanhf(W4[(size_t)d * 3 + 0] * e0 +
                                W4[(size_t)d * 3 + 1] * e1 +
                                W4[(size_t)d * 3 + 2] * e2 + b4[d]);
        out[d] = tanhf(hv1 * hv4 + hv2 + hv3);
    }
}

extern "C" void kernel_launch(void* const* d_in, const int* in_sizes, int n_in,
                              void* d_out, int out_size, void* d_ws, size_t ws_size,
                              hipStream_t stream) {
    const float* input = (const float*)d_in[0];
    const float* W1 = (const float*)d_in[1];
    const float* b1 = (const float*)d_in[2];
    const float* W2 = (const float*)d_in[3];
    const float* b2 = (const float*)d_in[4];
    const float* W3 = (const float*)d_in[5];
    const float* b3 = (const float*)d_in[6];
    const float* W4 = (const float*)d_in[7];
    const float* b4 = (const float*)d_in[8];
    float* out = (float*)d_out;
    float* feat = (float*)d_ws;

    hdc_features_kernel<<<1, 512, 0, stream>>>(input, feat);

    if (ws_size >= WS_NEED) {
        float* partial = feat + PART_OFF;
        hdc_dot_pipe<<<N_WAVES / 4, 256, 0, stream>>>(W1, W2, W3, feat, partial);
        hdc_tanh_kernel<<<(D_OUT + 255) / 256, 256, 0, stream>>>(
            partial, b1, b2, b3, W4, b4, feat, out);
    } else {
        hdc_gemv_fallback<<<D_OUT / 4, 256, 0, stream>>>(W1, b1, W2, b2, W3, b3,
                                                         W4, b4, feat, out);
    }
}